// Round 5
// baseline (1226.312 us; speedup 1.0000x reference)
//
#include <hip/hip_runtime.h>

#define BATCHN 32
#define SEQN   2048
#define INSZ   128
#define HN     128
#define G4     512   // 4*H

#define OUT_MAIN ((size_t)BATCHN * SEQN * 2 * HN)   // 16,777,216 floats

typedef float v2f __attribute__((ext_vector_type(2)));
typedef float v4f __attribute__((ext_vector_type(4)));

// packed 2xfp32 FMA: acc.lo += a.lo*b.lo; acc.hi += a.hi*b.hi
// inline asm forces all operands into arch VGPR pairs (no AGPR demotion).
#define PKFMA(ACC, A, B)                                        \
  asm("v_pk_fma_f32 %0, %1, %2, %0" : "+v"(ACC) : "v"(A), "v"(B))

__device__ __forceinline__ float fast_rcp(float x) {
  return __builtin_amdgcn_rcpf(x);   // v_rcp_f32, ~1 ulp
}

// quad butterfly sum via DPP: all 4 quad lanes end with the quad's sum
__device__ __forceinline__ float qsum(float x) {
  x += __int_as_float(__builtin_amdgcn_update_dpp(
      0, __float_as_int(x), 0xB1, 0xF, 0xF, true));   // quad_perm [1,0,3,2]
  x += __int_as_float(__builtin_amdgcn_update_dpp(
      0, __float_as_int(x), 0x4E, 0xF, 0xF, true));   // quad_perm [2,3,0,1]
  return x;
}

// broadcast quad lane Q to all 4 lanes of the quad (IMM = Q*0b01010101)
template <int IMM>
__device__ __forceinline__ float qperm(float x) {
  return __int_as_float(__builtin_amdgcn_update_dpp(
      0, __float_as_int(x), IMM, 0xF, 0xF, true));
}

// ---------------------------------------------------------------------------
// Precompute XW[m][n] = x_flat[m][:] @ Wi[:][n] + B[n]
// Register-tiled GEMM: 64x64 tile, K=128 resident in LDS. (~75 µs)
// ---------------------------------------------------------------------------
__global__ __launch_bounds__(256, 2) void precompute_xw(
    const float* __restrict__ x, const float* __restrict__ Wi,
    const float* __restrict__ B, float* __restrict__ XW) {
  __shared__ float As[INSZ][64];
  __shared__ float Bs[INSZ][64];

  const int tid = threadIdx.x;
  const int m0 = blockIdx.x * 64;
  const int n0 = blockIdx.y * 64;

  {
    const int row = tid & 63;
    const int k4b = tid >> 6;
    const float4* xs4 = (const float4*)(x + (size_t)(m0 + row) * INSZ);
#pragma unroll
    for (int it = 0; it < 8; it++) {
      const int k4 = k4b + (it << 2);
      float4 v = xs4[k4];
      As[k4 * 4 + 0][row] = v.x;
      As[k4 * 4 + 1][row] = v.y;
      As[k4 * 4 + 2][row] = v.z;
      As[k4 * 4 + 3][row] = v.w;
    }
  }
  {
    const int n4 = tid & 15;
    const int kb = tid >> 4;
#pragma unroll
    for (int it = 0; it < 8; it++) {
      const int k = kb + (it << 4);
      float4 v = *(const float4*)(Wi + (size_t)k * G4 + n0 + n4 * 4);
      *(float4*)&Bs[k][n4 * 4] = v;
    }
  }
  __syncthreads();

  const int tx = tid & 15;
  const int ty = tid >> 4;
  float4 acc0 = {0, 0, 0, 0}, acc1 = {0, 0, 0, 0};
  float4 acc2 = {0, 0, 0, 0}, acc3 = {0, 0, 0, 0};

#pragma unroll 8
  for (int k = 0; k < INSZ; k++) {
    const float4 a = *(const float4*)&As[k][ty * 4];
    const float4 bv = *(const float4*)&Bs[k][tx * 4];
    acc0.x += a.x * bv.x; acc0.y += a.x * bv.y; acc0.z += a.x * bv.z; acc0.w += a.x * bv.w;
    acc1.x += a.y * bv.x; acc1.y += a.y * bv.y; acc1.z += a.y * bv.z; acc1.w += a.y * bv.w;
    acc2.x += a.z * bv.x; acc2.y += a.z * bv.y; acc2.z += a.z * bv.z; acc2.w += a.z * bv.w;
    acc3.x += a.w * bv.x; acc3.y += a.w * bv.y; acc3.z += a.w * bv.z; acc3.w += a.w * bv.w;
  }

  const float4 bb = *(const float4*)(B + n0 + tx * 4);
  float* dst = XW + (size_t)(m0 + ty * 4) * G4 + n0 + tx * 4;
  float4 o;
  o.x = acc0.x + bb.x; o.y = acc0.y + bb.y; o.z = acc0.z + bb.z; o.w = acc0.w + bb.w;
  *(float4*)(dst + 0 * G4) = o;
  o.x = acc1.x + bb.x; o.y = acc1.y + bb.y; o.z = acc1.z + bb.z; o.w = acc1.w + bb.w;
  *(float4*)(dst + 1 * G4) = o;
  o.x = acc2.x + bb.x; o.y = acc2.y + bb.y; o.z = acc2.z + bb.z; o.w = acc2.w + bb.w;
  *(float4*)(dst + 2 * G4) = o;
  o.x = acc3.x + bb.x; o.y = acc3.y + bb.y; o.z = acc3.z + bb.z; o.w = acc3.w + bb.w;
  *(float4*)(dst + 3 * G4) = o;
}

// ---------------------------------------------------------------------------
// Recurrence: 64 blocks = chain (b, dir). 512 threads = 128 j x 4 k-quads.
// Thread (j,kq): Wh cols {j,j+128,j+256,j+384} for k in [kq*32,kq*32+32),
// stored as 64 float2 pairs (128 VGPRs, asm-pinned). Per step:
// 8 bank-rotated ds_read_b128, 64 v_pk_fma_f32 (packed fp32 = 2 MAC/instr),
// DPP quad-reduce, per-lane single-gate activation, quad_perm gather,
// c/h update. xw prefetch distance 2. 1 lgkm-only barrier/step.
// ---------------------------------------------------------------------------
__global__ __launch_bounds__(512, 2) void lstm_recur(
    const float* __restrict__ XW, const float* __restrict__ Wh,
    float* __restrict__ out) {
  const int tid = threadIdx.x;
  const int l   = tid & 63;
  const int w   = tid >> 6;
  const int kq  = l & 3;
  const int jl  = l >> 2;
  const int j   = w * 16 + jl;
  const int b   = blockIdx.x & 31;
  const int dir = blockIdx.x >> 5;

  __shared__ float hs[2][HN];

  // Wh fragment as packed pairs, bank-rotated k order:
  // pair (2i+p) covers k = kq*32 + ((i+2kq)&7)*4 + 2p + {0,1}
  v2f whp0[16], whp1[16], whp2[16], whp3[16];
#pragma unroll
  for (int i = 0; i < 8; i++) {
    const int ch = (i + 2 * kq) & 7;
    const int kb = kq * 32 + ch * 4;
#pragma unroll
    for (int p = 0; p < 2; p++) {
      const size_t r0 = (size_t)(kb + 2 * p + 0) * G4;
      const size_t r1 = (size_t)(kb + 2 * p + 1) * G4;
      whp0[2 * i + p] = (v2f){Wh[r0 + 0 * HN + j], Wh[r1 + 0 * HN + j]};
      whp1[2 * i + p] = (v2f){Wh[r0 + 1 * HN + j], Wh[r1 + 1 * HN + j]};
      whp2[2 * i + p] = (v2f){Wh[r0 + 2 * HN + j], Wh[r1 + 2 * HN + j]};
      whp3[2 * i + p] = (v2f){Wh[r0 + 3 * HN + j], Wh[r1 + 3 * HN + j]};
    }
  }

  // per-lane activation constants: lane kq applies only gate kq.
  // gate 2 (g) is tanh = 2*sig(2x)-1; others sigmoid.
  const bool k0 = (kq == 0), k1 = (kq == 1), k2 = (kq == 2);
  const float xsc = k2 ? -2.0f : -1.0f;
  const float asc = k2 ? 2.0f : 1.0f;
  const float abi = k2 ? -1.0f : 0.0f;

  if (tid < HN) hs[0][tid] = 0.f;
  float c = 0.f, h = 0.f;
  __syncthreads();

  const float* xwp = XW + (size_t)b * SEQN * G4 + (size_t)kq * HN + j;
  float xwA = xwp[(size_t)(dir ? SEQN - 1 : 0) * G4];
  float xwB = xwp[(size_t)(dir ? SEQN - 2 : 1) * G4];

#define LSTM_STEP(S, PAR, XWREG)                                               \
  {                                                                            \
    const int tpf = ((S) + 2 < SEQN) ? (S) + 2 : SEQN - 1;                     \
    const float xw_pf = xwp[(size_t)(dir ? (SEQN - 1 - tpf) : tpf) * G4];      \
    v2f ac0 = {0.f, 0.f}, ac1 = {0.f, 0.f};                                    \
    v2f ac2 = {0.f, 0.f}, ac3 = {0.f, 0.f};                                    \
    _Pragma("unroll")                                                          \
    for (int i = 0; i < 8; i++) {                                              \
      const int ch = (i + 2 * kq) & 7;                                         \
      const v4f hv = *(const v4f*)&hs[PAR][kq * 32 + ch * 4];                  \
      const v2f hlo = __builtin_shufflevector(hv, hv, 0, 1);                   \
      const v2f hhi = __builtin_shufflevector(hv, hv, 2, 3);                   \
      PKFMA(ac0, hlo, whp0[2 * i]); PKFMA(ac0, hhi, whp0[2 * i + 1]);          \
      PKFMA(ac1, hlo, whp1[2 * i]); PKFMA(ac1, hhi, whp1[2 * i + 1]);          \
      PKFMA(ac2, hlo, whp2[2 * i]); PKFMA(ac2, hhi, whp2[2 * i + 1]);          \
      PKFMA(ac3, hlo, whp3[2 * i]); PKFMA(ac3, hhi, whp3[2 * i + 1]);          \
    }                                                                          \
    float a0 = ac0.x + ac0.y, a1 = ac1.x + ac1.y;                              \
    float a2 = ac2.x + ac2.y, a3 = ac3.x + ac3.y;                              \
    a0 = qsum(a0); a1 = qsum(a1); a2 = qsum(a2); a3 = qsum(a3);                \
    float sel = k0 ? a0 : (k1 ? a1 : (k2 ? a2 : a3));                          \
    sel += XWREG;                                                              \
    const float e   = __expf(sel * xsc);                                       \
    const float r   = fast_rcp(1.0f + e);                                      \
    const float act = r * asc + abi;                                           \
    const float iv = qperm<0x00>(act);                                         \
    const float fv = qperm<0x55>(act);                                         \
    const float gv = qperm<0xAA>(act);                                         \
    const float ov = qperm<0xFF>(act);                                         \
    c = fv * c + iv * gv;                                                      \
    const float e2 = __expf(-2.0f * c);                                        \
    const float th = 2.0f * fast_rcp(1.0f + e2) - 1.0f;                        \
    h = ov * th;                                                               \
    if (kq == 0) {                                                             \
      hs[(PAR) ^ 1][j] = h;                                                    \
      out[((size_t)b * SEQN + (S)) * (2 * HN) + (size_t)dir * HN + j] = h;     \
    }                                                                          \
    asm volatile("s_waitcnt lgkmcnt(0)" ::: "memory");                         \
    __builtin_amdgcn_s_barrier();                                              \
    XWREG = xw_pf;                                                             \
  }

  for (int s = 0; s < SEQN; s += 2) {
    LSTM_STEP(s, 0, xwA);
    LSTM_STEP(s + 1, 1, xwB);
  }
#undef LSTM_STEP

  if (kq == 0) {
    float* carry = out + OUT_MAIN;
    carry[(size_t)(dir * 2 + 0) * BATCHN * HN + (size_t)b * HN + j] = h;
    carry[(size_t)(dir * 2 + 1) * BATCHN * HN + (size_t)b * HN + j] = c;
  }
}

// ---------------------------------------------------------------------------
// Fallback (workspace too small): compute x@Wi inline each step (slow, correct)
// ---------------------------------------------------------------------------
__global__ __launch_bounds__(512, 2) void lstm_recur_noxw(
    const float* __restrict__ x, const float* __restrict__ Wi,
    const float* __restrict__ Wh, const float* __restrict__ B,
    float* __restrict__ out) {
  const int j   = threadIdx.x;
  const int b   = blockIdx.x & 31;
  const int dir = blockIdx.x >> 5;

  __shared__ __align__(16) float hs[HN];
  __shared__ __align__(16) float xs[INSZ];
  __shared__ float gs[G4];

  float wh[HN];
#pragma unroll
  for (int k = 0; k < HN; k++) wh[k] = Wh[(size_t)k * G4 + j];
  const float bj = B[j];

  if (j < HN) hs[j] = 0.0f;
  float c = 0.0f, hlast = 0.0f;
  const int gtype = j >> 7;
  __syncthreads();

  for (int s = 0; s < SEQN; s++) {
    const int t = dir ? (SEQN - 1 - s) : s;
    if (j < INSZ / 4) {
      ((float4*)xs)[j] = ((const float4*)(x + ((size_t)b * SEQN + t) * INSZ))[j];
    }
    __syncthreads();

    float a0 = bj, a1 = 0.f, a2 = 0.f, a3 = 0.f;
    for (int k = 0; k < INSZ; k += 4) {
      a0 += xs[k + 0] * Wi[(size_t)(k + 0) * G4 + j] + hs[k + 0] * wh[k + 0];
      a1 += xs[k + 1] * Wi[(size_t)(k + 1) * G4 + j] + hs[k + 1] * wh[k + 1];
      a2 += xs[k + 2] * Wi[(size_t)(k + 2) * G4 + j] + hs[k + 2] * wh[k + 2];
      a3 += xs[k + 3] * Wi[(size_t)(k + 3) * G4 + j] + hs[k + 3] * wh[k + 3];
    }
    const float g = (a0 + a1) + (a2 + a3);

    float act;
    if (gtype == 2) act = 2.f * fast_rcp(1.f + __expf(-2.f * g)) - 1.f;
    else            act = fast_rcp(1.f + __expf(-g));
    gs[j] = act;
    __syncthreads();

    if (j < HN) {
      const float iv = gs[j];
      const float fv = gs[j + HN];
      const float gv = gs[j + 2 * HN];
      const float ov = gs[j + 3 * HN];
      c = fv * c + iv * gv;
      hlast = ov * (2.f * fast_rcp(1.f + __expf(-2.f * c)) - 1.f);
      hs[j] = hlast;
      out[((size_t)b * SEQN + s) * (2 * HN) + (size_t)dir * HN + j] = hlast;
    }
    __syncthreads();
  }

  if (j < HN) {
    float* carry = out + OUT_MAIN;
    carry[((size_t)(dir * 2 + 0)) * BATCHN * HN + (size_t)b * HN + j] = hlast;
    carry[((size_t)(dir * 2 + 1)) * BATCHN * HN + (size_t)b * HN + j] = c;
  }
}

extern "C" void kernel_launch(void* const* d_in, const int* in_sizes, int n_in,
                              void* d_out, int out_size, void* d_ws, size_t ws_size,
                              hipStream_t stream) {
  const float* x  = (const float*)d_in[0];
  const float* Wi = (const float*)d_in[1];
  const float* Wh = (const float*)d_in[2];
  const float* B  = (const float*)d_in[3];
  float* out = (float*)d_out;

  const size_t xw_bytes = (size_t)BATCHN * SEQN * G4 * sizeof(float);  // 128 MiB
  if (ws_size >= xw_bytes) {
    float* XW = (float*)d_ws;
    precompute_xw<<<dim3(1024, 8), dim3(256), 0, stream>>>(x, Wi, B, XW);
    lstm_recur<<<dim3(64), dim3(512), 0, stream>>>(XW, Wh, out);
  } else {
    lstm_recur_noxw<<<dim3(64), dim3(512), 0, stream>>>(x, Wi, Wh, B, out);
  }
}